// Round 9
// baseline (103.569 us; speedup 1.0000x reference)
//
#include <hip/hip_runtime.h>
#include <cmath>
#include <complex>
#include <cstring>
#include <algorithm>

#define DIM_IN  288
#define DIM_SHD 9
#define NB      10
#define NH      16
#define EPB     16
#define BLOCK   256
#define NINSTR  11
#define XSTR    292
#define ZW      84          // per-wave z row stride (floats); 16 rows
#define ZBUF    1344        // 16*84 floats per wave
#define W2B_ELEMS (NINSTR * 32 * 32 * 32)   // [ins][u][w][t0..31]; t=16 holds b2, t>16 zero

// LDS pool (floats), total 10240 fl = 40960 B -> 4 blocks/CU (163840 = full pool):
//   s_xo : [0, 4672)             16*292, x staging; reused for out gather
//   s_zw : [4672, 10048)         4 waves x 1344, PRIVATE per-wave z
//   s_sh : [10048, 10240)        16*12
//   s_hb : alias wave-3 z buffer (512 ushort; dead after hB hoist, barrier-protected)
#define OFF_XO 0
#define OFF_ZW 4672
#define OFF_SH 10048
#define POOLSZ 10240

typedef __attribute__((ext_vector_type(8))) short  short8b;
typedef __attribute__((ext_vector_type(4))) float  f32x4;

__device__ float g_C[NINSTR][125];

__device__ __forceinline__ unsigned short f2bf(float f) {
  unsigned int u = __float_as_uint(f);
  unsigned int r = (u + 0x7fffu + ((u >> 16) & 1u)) >> 16;   // RNE
  return (unsigned short)r;
}

// W2 -> bf16 [ins][u][w][t]; t<16 = W2 row t, t==16 = b2 (hB carries 1.0 there), t>16 = 0
__global__ __launch_bounds__(256) void prep_w2(const float* __restrict__ W2,
                                               const float* __restrict__ b2,
                                               unsigned short* __restrict__ W2b) {
  int gid = blockIdx.x * 256 + threadIdx.x;
  if (gid < W2B_ELEMS) {
    int c = gid >> 5, t = gid & 31;          // c = ins*1024 + u*32 + w
    float v = (t < 16) ? W2[(size_t)t * 11264 + c] : (t == 16 ? b2[c] : 0.0f);
    W2b[gid] = f2bf(v);
  }
}

// ---- per-WAVE z-phase: 16 edges x 16 u(half) = 256 tasks over 64 lanes ----
// writes zw[e*ZW + k*16 + ul]; wave-internal only, no barrier needed.
template<int INS,int D1,int D2,int D3,int OFF1,int OFF2>
__device__ __forceinline__ void z_phase_w(
    int lane, int b_uh, const float* __restrict__ s_x,
    const float* __restrict__ s_sh, float* __restrict__ zw)
{
  const float* __restrict__ Cp = g_C[INS];
  #pragma unroll
  for (int s = 0; s < 4; ++s) {
    int id = lane + s * 64;
    int e = id >> 4, ul = id & 15;
    const float* xe = s_x + e * XSTR + OFF1 + (b_uh * 16 + ul) * D1;
    float zk[D3];
    #pragma unroll
    for (int k = 0; k < D3; ++k) zk[k] = 0.f;
    #pragma unroll
    for (int i = 0; i < D1; ++i) {
      float xv = xe[i];
      #pragma unroll
      for (int j = 0; j < D2; ++j) {
        float pr = xv * s_sh[e * 12 + OFF2 + j];
        #pragma unroll
        for (int k = 0; k < D3; ++k)
          zk[k] = fmaf(Cp[(i * D2 + j) * D3 + k], pr, zk[k]);
      }
    }
    #pragma unroll
    for (int k = 0; k < D3; ++k) zw[e * ZW + k * 16 + ul] = zk[k];
  }
}

// ---- MFMA weight-gen (bias folded via t=16) + u-contraction from private z ----
template<int INS,int D3,int SB>
__device__ __forceinline__ void contract(
    int ls, int lq, int a_wt, int b_uh,
    const unsigned short* __restrict__ W2b,
    const float* __restrict__ zw, short8b hB, float (&acc)[4][9])
{
  const unsigned short* Ap =
      W2b + ((size_t)(INS * 32 + b_uh * 16) * 32 + a_wt * 16 + ls) * 32 + lq * 8;
  const float* zb = zw + ls * ZW;
  const f32x4 zero4 = {0.f, 0.f, 0.f, 0.f};

  short8b Ra = *(const short8b*)(Ap);
  f32x4 w_cur = __builtin_amdgcn_mfma_f32_16x16x32_bf16(Ra, hB, zero4, 0, 0, 0);
  short8b Rb = *(const short8b*)(Ap + 1024);

  #pragma unroll
  for (int c = 0; c < 4; ++c) {
    float4 zq[D3];
    #pragma unroll
    for (int k = 0; k < D3; ++k)
      zq[k] = *(const float4*)(zb + k * 16 + c * 4);   // stride-84 rows: 2-way, free
    #pragma unroll
    for (int i = 0; i < 4; ++i) {
      const int g = c * 4 + i;              // local u index (0..15)
      f32x4 w_next;
      if (g < 15) {
        w_next = __builtin_amdgcn_mfma_f32_16x16x32_bf16(Rb, hB, zero4, 0, 0, 0);
        if (g + 2 < 16) Rb = *(const short8b*)(Ap + (size_t)(g + 2) * 1024);
      }
      #pragma unroll
      for (int k = 0; k < D3; ++k) {
        const float zz = (i == 0) ? zq[k].x : (i == 1) ? zq[k].y
                       : (i == 2) ? zq[k].z : zq[k].w;
        acc[0][SB + k] = fmaf(w_cur[0], zz, acc[0][SB + k]);
        acc[1][SB + k] = fmaf(w_cur[1], zz, acc[1][SB + k]);
        acc[2][SB + k] = fmaf(w_cur[2], zz, acc[2][SB + k]);
        acc[3][SB + k] = fmaf(w_cur[3], zz, acc[3][SB + k]);
      }
      if (g < 15) w_cur = w_next;
    }
  }
}

// NOTE (journal): VGPR cap = 256 / (2nd launch_bounds arg) on this hipcc:
// arg=2 -> 128 (r4/r5/r7/r8), arg=4 -> 64 (r3/r6, catastrophic spill). Keep 2.
__global__ __launch_bounds__(BLOCK, 2) void conv_kernel(
    const float* __restrict__ xg, const float* __restrict__ shg,
    const float* __restrict__ dist, const float* __restrict__ freq,
    const float* __restrict__ W1, const float* __restrict__ b1,
    const unsigned short* __restrict__ W2b,
    float* __restrict__ out)
{
  __shared__ float s_pool[POOLSZ];        // 40960 B exactly
  float* s_xo = s_pool + OFF_XO;
  float* s_sh = s_pool + OFF_SH;

  const int tid = threadIdx.x;
  const int e0 = blockIdx.x * EPB;
  const int lane = tid & 63;
  const int ls = lane & 15;       // e-col (B/C cols) & w-row selector (A rows)
  const int lq = lane >> 4;       // 0..3 k-slice / output reg quad
  const int wid = tid >> 6;       // 0..3
  const int a_wt = wid >> 1;      // w-tile 0/1
  const int b_uh = wid & 1;       // u-half 0/1
  float* zw = s_pool + OFF_ZW + wid * ZBUF;                    // private z
  unsigned short* s_hb = (unsigned short*)(s_pool + OFF_ZW + 3 * ZBUF); // alias w3

  // ---- prologue 1: stage x (coalesced) + sh ----
  for (int i4 = tid; i4 < EPB * 72; i4 += BLOCK) {
    int e = i4 / 72, r = i4 - e * 72;
    *(float4*)(s_xo + e * XSTR + r * 4) =
        *(const float4*)(xg + (size_t)(e0 + e) * DIM_IN + r * 4);
  }
  if (tid < EPB * DIM_SHD) {
    int e = tid / DIM_SHD, c = tid - (tid / DIM_SHD) * DIM_SHD;
    s_sh[e * 12 + c] = shg[(size_t)(e0 + e) * DIM_SHD + c];
  }
  __syncthreads();

  // ---- prologue 2: radial MLP (basis inline), h -> s_hb (aliased) ----
  {
    int e = tid >> 4, t = tid & 15;
    float d  = dist[e0 + e];
    float xv = d * 0.25f;
    float x2 = xv * xv, x4 = x2 * x2, x5 = x4 * xv;
    float env = 1.0f / xv + x5 * fmaf(xv, fmaf(xv, -21.0f, 48.0f), -28.0f);
    env = (xv < 1.0f) ? env : 0.0f;
    float v = b1[t];
    #pragma unroll
    for (int n = 0; n < NB; ++n)
      v = fmaf(env * sinf(freq[n] * xv), W1[n * NH + t], v);
    v = v / (1.0f + expf(-v));          // silu
    s_hb[e * 32 + t] = f2bf(v);
    s_hb[e * 32 + t + 16] = (t == 0) ? (unsigned short)0x3F80 : (unsigned short)0;
  }
  __syncthreads();
  short8b hB = *(const short8b*)(s_hb + ls * 32 + lq * 8);
  __syncthreads();   // all waves hold hB before wave 3 overwrites its z buffer

  float acc[4][9];
  #pragma unroll
  for (int r = 0; r < 4; ++r)
    #pragma unroll
    for (int a = 0; a < 9; ++a) acc[r][a] = 0.f;

  // ---- main loop: fully wave-independent, ZERO barriers ----
  z_phase_w< 0, 1, 1, 1,   0, 0>(lane, b_uh, s_xo, s_sh, zw);
  contract< 0, 1, 0>(ls, lq, a_wt, b_uh, W2b, zw, hB, acc);
  z_phase_w< 1, 1, 3, 3,   0, 1>(lane, b_uh, s_xo, s_sh, zw);
  contract< 1, 3, 1>(ls, lq, a_wt, b_uh, W2b, zw, hB, acc);
  z_phase_w< 2, 1, 5, 5,   0, 4>(lane, b_uh, s_xo, s_sh, zw);
  contract< 2, 5, 4>(ls, lq, a_wt, b_uh, W2b, zw, hB, acc);
  z_phase_w< 3, 3, 1, 3,  32, 0>(lane, b_uh, s_xo, s_sh, zw);
  contract< 3, 3, 1>(ls, lq, a_wt, b_uh, W2b, zw, hB, acc);
  z_phase_w< 4, 3, 3, 1,  32, 1>(lane, b_uh, s_xo, s_sh, zw);
  contract< 4, 1, 0>(ls, lq, a_wt, b_uh, W2b, zw, hB, acc);
  z_phase_w< 5, 3, 3, 5,  32, 1>(lane, b_uh, s_xo, s_sh, zw);
  contract< 5, 5, 4>(ls, lq, a_wt, b_uh, W2b, zw, hB, acc);
  z_phase_w< 6, 3, 5, 3,  32, 4>(lane, b_uh, s_xo, s_sh, zw);
  contract< 6, 3, 1>(ls, lq, a_wt, b_uh, W2b, zw, hB, acc);
  z_phase_w< 7, 5, 1, 5, 128, 0>(lane, b_uh, s_xo, s_sh, zw);
  contract< 7, 5, 4>(ls, lq, a_wt, b_uh, W2b, zw, hB, acc);
  z_phase_w< 8, 5, 3, 3, 128, 1>(lane, b_uh, s_xo, s_sh, zw);
  contract< 8, 3, 1>(ls, lq, a_wt, b_uh, W2b, zw, hB, acc);
  z_phase_w< 9, 5, 5, 1, 128, 4>(lane, b_uh, s_xo, s_sh, zw);
  contract< 9, 1, 0>(ls, lq, a_wt, b_uh, W2b, zw, hB, acc);
  z_phase_w<10, 5, 5, 5, 128, 4>(lane, b_uh, s_xo, s_sh, zw);
  contract<10, 5, 4>(ls, lq, a_wt, b_uh, W2b, zw, hB, acc);

  // ---- epilogue: cross-wave u-half reduction into s_xo, coalesced store ----
  __syncthreads();   // everyone done reading s_xo (x) before overwrite
  if (b_uh == 1) {
    float* row = s_xo + ls * XSTR;
    #pragma unroll
    for (int r = 0; r < 4; ++r) {
      int w = a_wt * 16 + lq * 4 + r;
      row[w] = acc[r][0];
      #pragma unroll
      for (int k = 0; k < 3; ++k) row[32 + w * 3 + k] = acc[r][1 + k];
      #pragma unroll
      for (int k = 0; k < 5; ++k) row[128 + w * 5 + k] = acc[r][4 + k];
    }
  }
  __syncthreads();
  if (b_uh == 0) {
    float* row = s_xo + ls * XSTR;
    #pragma unroll
    for (int r = 0; r < 4; ++r) {
      int w = a_wt * 16 + lq * 4 + r;
      row[w] += acc[r][0];
      #pragma unroll
      for (int k = 0; k < 3; ++k) row[32 + w * 3 + k] += acc[r][1 + k];
      #pragma unroll
      for (int k = 0; k < 5; ++k) row[128 + w * 5 + k] += acc[r][4 + k];
    }
  }
  __syncthreads();
  for (int i4 = tid; i4 < EPB * 72; i4 += BLOCK) {
    int e = i4 / 72, r = i4 - e * 72;
    float4 v = *(const float4*)(s_xo + e * XSTR + r * 4);
    *(float4*)(out + (size_t)(e0 + e) * DIM_IN + r * 4) = v;
  }
}

// ===================== host-side Wigner-3j (mirrors reference) =====================
typedef std::complex<double> cd;

static double factd(int n) { double r = 1; for (int i = 2; i <= n; ++i) r *= i; return r; }

static double su2_cg(int j1, int j2, int j3, int m1, int m2, int m3) {
  if (m3 != m1 + m2) return 0.0;
  int vmin = std::max(std::max(-j1 + j2 + m3, -j1 + m1), 0);
  int vmax = std::min(std::min(j2 + j3 + m1, j3 - j1 + j2), j3 + m3);
  if (vmax < vmin) return 0.0;
  double c = std::sqrt(
      factd(2*j3+1) * factd(j3+j1-j2) * factd(j3-j1+j2) * factd(j1+j2-j3) / factd(j1+j2+j3+1)
      * factd(j3+m3) * factd(j3-m3)
      / (factd(j1+m1) * factd(j1-m1) * factd(j2+m2) * factd(j2-m2)));
  double s = 0.0;
  for (int v = vmin; v <= vmax; ++v) {
    double sg = ((v + j2 + m2) & 1) ? -1.0 : 1.0;
    s += sg * factd(j2+j3+m1-v) * factd(j1-m1+v)
         / (factd(v) * factd(j3-j1+j2-v) * factd(j3+m3-v) * factd(v+j1-j2-m3));
  }
  return c * s;
}

static void qmat(int l, cd q[5][5]) {
  for (int a = 0; a < 5; ++a) for (int b = 0; b < 5; ++b) q[a][b] = cd(0, 0);
  const double s = 1.0 / std::sqrt(2.0);
  for (int m = -l; m < 0; ++m) {
    q[l + m][l - m] = cd(s, 0);
    q[l + m][l + m] = cd(0, -s);
  }
  q[l][l] = cd(1, 0);
  for (int m = 1; m <= l; ++m) {
    double sg = (m & 1) ? -1.0 : 1.0;
    q[l + m][l + m] = cd(sg * s, 0);
    q[l + m][l - m] = cd(0, sg * s);
  }
  cd ph = (l == 0) ? cd(1, 0) : (l == 1) ? cd(0, -1) : cd(-1, 0);  // (-i)^l
  for (int a = 0; a < 5; ++a) for (int b = 0; b < 5; ++b) q[a][b] *= ph;
}

static void wigner3j(int l1, int l2, int l3, double C[5][5][5]) {
  int d1 = 2*l1+1, d2 = 2*l2+1, d3 = 2*l3+1;
  cd q1[5][5], q2[5][5], q3[5][5];
  qmat(l1, q1); qmat(l2, q2); qmat(l3, q3);
  double norm2 = 0;
  for (int j = 0; j < d1; ++j)
    for (int l = 0; l < d2; ++l)
      for (int n = 0; n < d3; ++n) {
        cd sum(0, 0);
        for (int i = 0; i < d1; ++i)
          for (int k = 0; k < d2; ++k)
            for (int m = 0; m < d3; ++m) {
              double cg = su2_cg(l1, l2, l3, i - l1, k - l2, m - l3);
              if (cg != 0.0) sum += q1[i][j] * q2[k][l] * std::conj(q3[m][n]) * cg;
            }
        C[j][l][n] = sum.real();
        norm2 += C[j][l][n] * C[j][l][n];
      }
  double nrm = std::sqrt(norm2);
  if (nrm > 0)
    for (int j = 0; j < d1; ++j)
      for (int l = 0; l < d2; ++l)
        for (int n = 0; n < d3; ++n) C[j][l][n] /= nrm;
}

static void build_C_host(float C_out[NINSTR][125]) {
  const int L1[NINSTR] = {0,0,0,1,1,1,1,2,2,2,2};
  const int L2[NINSTR] = {0,1,2,0,1,1,2,0,1,2,2};
  const int L3[NINSTR] = {0,1,2,1,0,2,1,2,1,0,2};
  std::memset(C_out, 0, sizeof(float) * NINSTR * 125);
  for (int ins = 0; ins < NINSTR; ++ins) {
    int l1 = L1[ins], l2 = L2[ins], l3 = L3[ins];
    int d1 = 2*l1+1, d2 = 2*l2+1, d3 = 2*l3+1;
    double C[5][5][5];
    wigner3j(l1, l2, l3, C);
    double fan = (l3 == 0) ? 96.0 : 128.0;
    double pw = std::sqrt((2*l3+1) / fan);
    for (int i = 0; i < d1; ++i)
      for (int j = 0; j < d2; ++j)
        for (int k = 0; k < d3; ++k)
          C_out[ins][(i * d2 + j) * d3 + k] = (float)(pw * C[i][j][k]);
  }
}

extern "C" void kernel_launch(void* const* d_in, const int* in_sizes, int n_in,
                              void* d_out, int out_size, void* d_ws, size_t ws_size,
                              hipStream_t stream) {
  static float hC[NINSTR][125];
  build_C_host(hC);
  void* dC = nullptr;
  hipGetSymbolAddress(&dC, HIP_SYMBOL(g_C));
  hipMemcpyAsync(dC, hC, sizeof(hC), hipMemcpyHostToDevice, stream);

  const float* xg   = (const float*)d_in[0];
  const float* shg  = (const float*)d_in[1];
  const float* dist = (const float*)d_in[2];
  const float* freq = (const float*)d_in[3];
  const float* W1   = (const float*)d_in[4];
  const float* b1   = (const float*)d_in[5];
  const float* W2   = (const float*)d_in[6];
  const float* b2   = (const float*)d_in[7];
  float* out = (float*)d_out;
  unsigned short* W2b = (unsigned short*)d_ws;    // 720896 bytes

  prep_w2<<<(W2B_ELEMS + 255) / 256, 256, 0, stream>>>(W2, b2, W2b);

  int E = in_sizes[2];            // 16384
  int blocks = E / EPB;           // 1024
  conv_kernel<<<blocks, BLOCK, 0, stream>>>(xg, shg, dist, freq, W1, b1, W2b, out);
}